// Round 4
// baseline (1604.874 us; speedup 1.0000x reference)
//
#include <hip/hip_runtime.h>
#include <float.h>

#define NPTS 4096
#define BN   16384
#define DT   128
#define DIN  64

typedef short v8s __attribute__((ext_vector_type(8)));
typedef float v4f __attribute__((ext_vector_type(4)));

__device__ __forceinline__ unsigned short f2bf(float f) {
    union { float f; unsigned u; } v; v.f = f;
    unsigned r = v.u + 0x7fff + ((v.u >> 16) & 1);
    return (unsigned short)(r >> 16);
}
__device__ __forceinline__ float bf2f(unsigned short s) {
    union { unsigned u; float f; } v; v.u = ((unsigned)s) << 16;
    return v.f;
}
__device__ __forceinline__ unsigned pack2(float lo, float hi) {
    return (unsigned)f2bf(lo) | ((unsigned)f2bf(hi) << 16);
}

// ------------------------------------------------------------------ prep
__global__ __launch_bounds__(256) void prep_kernel(
    const float* __restrict__ pos, const float* __restrict__ d2w,
    const float* __restrict__ g1w, const float* __restrict__ g2w,
    const float* __restrict__ fc2w,
    float4* __restrict__ pos4, unsigned short* __restrict__ wB,
    unsigned short* __restrict__ fc2wT) {
    int i = blockIdx.x * 256 + threadIdx.x;
    if (i < BN) {
        float p0 = pos[i*3], p1 = pos[i*3+1], p2 = pos[i*3+2];
        pos4[i] = make_float4(p0, p1, p2, fmaf(p2, p2, fmaf(p1, p1, p0*p0)));
    } else if (i < BN + 3*16384) {
        int e = i - BN; int m = e >> 14; e &= 16383;
        int k = e >> 7, n = e & 127;
        const float* W = (m == 0) ? d2w : (m == 1) ? g1w : g2w;
        float val = W[k*128 + n];
        int tile = n >> 4, nl = n & 15, ks = k >> 5, q = (k >> 3) & 3, j = k & 7;
        wB[m*16384 + ((tile*4 + ks)*64 + q*16 + nl)*8 + j] = f2bf(val);
    } else if (i < BN + 3*16384 + 8192) {
        int e = i - BN - 3*16384;
        int o = e >> 7, c = e & 127;
        fc2wT[o*128 + c] = f2bf(fc2w[c*64 + o]);
    }
}

// ------------------------------------------------------------------ knn
// Exact top-16 via threshold pruning (tau = 16th smallest of 64 lane-minima
// bounds the true 16th distance; candidates <= tau compacted and sorted).
#define CSW(da,ia,db,ib) { bool sw_ = (da>db)||((da==db)&&(ia>ib)); \
    float td_=sw_?db:da, tD_=sw_?da:db; int ti_=sw_?ib:ia, tI_=sw_?ia:ib; \
    da=td_; db=tD_; ia=ti_; ib=tI_; }

__global__ __launch_bounds__(256, 4) void knn_kernel(const float4* __restrict__ pos4,
                                                     int* __restrict__ knnb) {
    __shared__ float scd[8][256];
    __shared__ int   sci[8][256];
    int t = threadIdx.x, lane = t & 63, w = t >> 6;
    int n0 = blockIdx.x * 8 + w * 2;
    int base = n0 & ~(NPTS - 1);
    float4 pa = pos4[n0], pb = pos4[n0 + 1];

    float mina = FLT_MAX, minb = FLT_MAX;
    for (int m = lane; m < NPTS; m += 64) {
        float4 c = pos4[base + m];
        float da = (pa.w + c.w) - 2.0f * fmaf(pa.z, c.z, fmaf(pa.y, c.y, pa.x*c.x));
        float db = (pb.w + c.w) - 2.0f * fmaf(pb.z, c.z, fmaf(pb.y, c.y, pb.x*c.x));
        mina = fminf(mina, da); minb = fminf(minb, db);
    }
    float taua, taub;
    {
        float cur = mina;
        for (int r = 0; r < 16; r++) {
            float bd = cur;
            for (int off = 32; off; off >>= 1) bd = fminf(bd, __shfl_xor(bd, off, 64));
            taua = bd;
            if (cur == bd) cur = FLT_MAX;
        }
        cur = minb;
        for (int r = 0; r < 16; r++) {
            float bd = cur;
            for (int off = 32; off; off >>= 1) bd = fminf(bd, __shfl_xor(bd, off, 64));
            taub = bd;
            if (cur == bd) cur = FLT_MAX;
        }
    }
    int ca = 0, cb = 0;
    for (int m = lane; m < NPTS; m += 64) {
        float4 c = pos4[base + m];
        float da = (pa.w + c.w) - 2.0f * fmaf(pa.z, c.z, fmaf(pa.y, c.y, pa.x*c.x));
        float db = (pb.w + c.w) - 2.0f * fmaf(pb.z, c.z, fmaf(pb.y, c.y, pb.x*c.x));
        bool ta = da <= taua, tb_ = db <= taub;
        unsigned long long ma = __ballot(ta), mb = __ballot(tb_);
        unsigned long long lower = (1ull << lane) - 1ull;
        if (ta) {
            int p_ = ca + __popcll(ma & lower);
            if (p_ < 256) { scd[w*2][p_] = da; sci[w*2][p_] = base + m; }
        }
        if (tb_) {
            int p_ = cb + __popcll(mb & lower);
            if (p_ < 256) { scd[w*2+1][p_] = db; sci[w*2+1][p_] = base + m; }
        }
        ca += __popcll(ma); cb += __popcll(mb);
    }
    if (ca > 256) ca = 256;
    if (cb > 256) cb = 256;
    for (int i = ca + lane; i < 256; i += 64) { scd[w*2][i]   = FLT_MAX; sci[w*2][i]   = 0x7fffffff; }
    for (int i = cb + lane; i < 256; i += 64) { scd[w*2+1][i] = FLT_MAX; sci[w*2+1][i] = 0x7fffffff; }
    __syncthreads();

    for (int pt = 0; pt < 2; pt++) {
        int s = w*2 + pt;
        float4 dv = *(const float4*)&scd[s][lane*4];
        int4   iv = *(const int4*)&sci[s][lane*4];
        CSW(dv.x, iv.x, dv.y, iv.y);
        CSW(dv.z, iv.z, dv.w, iv.w);
        CSW(dv.x, iv.x, dv.z, iv.z);
        CSW(dv.y, iv.y, dv.w, iv.w);
        CSW(dv.y, iv.y, dv.z, iv.z);
        int p = 0, myres = 0;
        for (int r = 0; r < 16; r++) {
            float hd = p==0 ? dv.x : p==1 ? dv.y : p==2 ? dv.z : p==3 ? dv.w : FLT_MAX;
            int   hi = p==0 ? iv.x : p==1 ? iv.y : p==2 ? iv.z : p==3 ? iv.w : 0x7fffffff;
            float bd = hd; int bi = hi;
            for (int off = 32; off; off >>= 1) {
                float od = __shfl_xor(bd, off, 64);
                int   oi = __shfl_xor(bi, off, 64);
                if (od < bd || (od == bd && oi < bi)) { bd = od; bi = oi; }
            }
            if (hi == bi) p++;
            if (lane == r) myres = bi;
        }
        if (lane < 16) knnb[(n0 + pt)*16 + lane] = myres;
    }
}

// ------------------------------------------------------------------ feat
__global__ __launch_bounds__(256) void feat_kernel(
    const float* __restrict__ x,
    const float* __restrict__ fc1w, const float* __restrict__ fc1b,
    const float* __restrict__ wq, const float* __restrict__ wk,
    const float* __restrict__ wv,
    unsigned short* __restrict__ qb, unsigned short* __restrict__ kb,
    unsigned short* __restrict__ vb) {
    __shared__ float xs[16][64];
    __shared__ float hs[16][128];
    int rb = blockIdx.x * 16;
    int t  = threadIdx.x;

    for (int i = t; i < 16*64; i += 256) xs[i>>6][i&63] = x[rb*64 + i];
    __syncthreads();

    int f4 = (t & 31) * 4;
    int r0 = (t >> 5) * 2, r1 = r0 + 1;
    float a0[4], a1[4];
#pragma unroll
    for (int jf = 0; jf < 4; jf++) { a0[jf] = fc1b[f4+jf]; a1[jf] = fc1b[f4+jf]; }
#pragma unroll 4
    for (int c = 0; c < 64; c += 4) {
        float s0[4], s1[4];
        *(float4*)s0 = *(const float4*)&xs[r0][c];
        *(float4*)s1 = *(const float4*)&xs[r1][c];
#pragma unroll
        for (int jc = 0; jc < 4; jc++) {
            float w[4];
            *(float4*)w = *(const float4*)&fc1w[(c+jc)*128 + f4];
#pragma unroll
            for (int jf = 0; jf < 4; jf++) {
                a0[jf] = fmaf(s0[jc], w[jf], a0[jf]);
                a1[jf] = fmaf(s1[jc], w[jf], a1[jf]);
            }
        }
    }
    *(float4*)&hs[r0][f4] = *(float4*)a0;
    *(float4*)&hs[r1][f4] = *(float4*)a1;
    __syncthreads();

    const float* Ws[3] = { wq, wk, wv };
    unsigned short* Os[3] = { qb, kb, vb };
    for (int mtx = 0; mtx < 3; mtx++) {
        const float* __restrict__ W = Ws[mtx];
#pragma unroll
        for (int jf = 0; jf < 4; jf++) { a0[jf] = 0.f; a1[jf] = 0.f; }
#pragma unroll 4
        for (int c = 0; c < 128; c += 4) {
            float s0[4], s1[4];
            *(float4*)s0 = *(const float4*)&hs[r0][c];
            *(float4*)s1 = *(const float4*)&hs[r1][c];
#pragma unroll
            for (int jc = 0; jc < 4; jc++) {
                float w[4];
                *(float4*)w = *(const float4*)&W[(c+jc)*128 + f4];
#pragma unroll
                for (int jf = 0; jf < 4; jf++) {
                    a0[jf] = fmaf(s0[jc], w[jf], a0[jf]);
                    a1[jf] = fmaf(s1[jc], w[jf], a1[jf]);
                }
            }
        }
        unsigned short* O = Os[mtx];
        uint2 s0v, s1v;
        s0v.x = pack2(a0[0], a0[1]); s0v.y = pack2(a0[2], a0[3]);
        s1v.x = pack2(a1[0], a1[1]); s1v.y = pack2(a1[2], a1[3]);
        *(uint2*)&O[(size_t)(rb+r0)*128 + f4] = s0v;
        *(uint2*)&O[(size_t)(rb+r1)*128 + f4] = s1v;
    }
}

// ------------------------------------------------------------------ fused
// Per wave per point: hd(A-frag regs) -> pe=hd@d2 (B from global)
// -> vpe=v+pe kept in regs; a=q-k+pe -> LDS transpose -> gh=relu(a@g1) (LDS B)
// -> LDS transpose -> gm=gh@g2 (B global) -> softmax -> attn store; res=sum
// attn*vpe -> fc2 epilogue. No intermediate global tensors.
__global__ __launch_bounds__(256, 3) void fused_kernel(
    const float4* __restrict__ pos4, const int* __restrict__ knnb,
    const unsigned short* __restrict__ qb, const unsigned short* __restrict__ kb,
    const unsigned short* __restrict__ vb,
    const unsigned short* __restrict__ wB,
    const float* __restrict__ d1w, const float* __restrict__ d1b,
    const float* __restrict__ d2b, const float* __restrict__ g1b,
    const float* __restrict__ g2b,
    const unsigned short* __restrict__ fc2wT, const float* __restrict__ fc2b,
    const float* __restrict__ x,
    float* __restrict__ out, float* __restrict__ attn) {
    __shared__ unsigned short g1s[16384];   // 32 KB
    __shared__ unsigned short tb[4][2048];  // 4 KB/wave transpose buf (reused as res)
    int t = threadIdx.x;
    {
        const uint4* src = (const uint4*)(wB + 16384);
        uint4* dst = (uint4*)g1s;
        for (int i = t; i < 2048; i += 256) dst[i] = src[i];
    }
    __syncthreads();

    const unsigned short* d2B = wB;           // 32 KB, L2-resident
    const unsigned short* g2B = wB + 32768;   // 32 KB, L2-resident
    int lane = t & 63, w = t >> 6;
    int col = lane & 15, quad = lane >> 4;
    const float inv_s = 0.08838834764831845f;   // 1/sqrt(128)

    for (int it = 0; it < 4; it++) {
        int n = (blockIdx.x * 4 + w) * 4 + it;
        int jid = knnb[n*16 + col];
        float4 pn = pos4[n];
        float4 pj = pos4[jid];
        float r0 = pn.x - pj.x, r1 = pn.y - pj.y, r2 = pn.z - pj.z;

        // hd in A-frag layout (lane: row m=col, features ks*32+quad*8..+7)
        v8s af[4];
#pragma unroll
        for (int ks = 0; ks < 4; ks++) {
            int fb = ks*32 + quad*8;
            float w0[8], w1[8], w2[8], bb[8];
            *(float4*)&w0[0] = *(const float4*)&d1w[fb];
            *(float4*)&w0[4] = *(const float4*)&d1w[fb+4];
            *(float4*)&w1[0] = *(const float4*)&d1w[128+fb];
            *(float4*)&w1[4] = *(const float4*)&d1w[128+fb+4];
            *(float4*)&w2[0] = *(const float4*)&d1w[256+fb];
            *(float4*)&w2[4] = *(const float4*)&d1w[256+fb+4];
            *(float4*)&bb[0] = *(const float4*)&d1b[fb];
            *(float4*)&bb[4] = *(const float4*)&d1b[fb+4];
#pragma unroll
            for (int j = 0; j < 8; j++) {
                float h = fmaf(r2, w2[j], fmaf(r1, w1[j], fmaf(r0, w0[j], bb[j])));
                af[ks][j] = (short)f2bf(fmaxf(h, 0.0f));
            }
        }

        // pe = hd @ d2
        v4f acc[8];
#pragma unroll
        for (int tt = 0; tt < 8; tt++)
#pragma unroll
            for (int rr = 0; rr < 4; rr++) acc[tt][rr] = 0.0f;
#pragma unroll
        for (int ks = 0; ks < 4; ks++) {
#pragma unroll
            for (int tt = 0; tt < 8; tt++) {
                v8s b = *(const v8s*)&d2B[((tt*4 + ks) << 9) + (lane << 3)];
                acc[tt] = __builtin_amdgcn_mfma_f32_16x16x32_bf16(af[ks], b, acc[tt], 0, 0, 0);
            }
        }

        // vpe (regs) and a = q-k+pe -> transpose buf (bf16)
        float vpe[8][4];
#pragma unroll
        for (int tt = 0; tt < 8; tt++) {
            int cg = tt*16 + col;
            float bias = d2b[cg];
            float qv = bf2f(qb[(size_t)n*128 + cg]);
#pragma unroll
            for (int r = 0; r < 4; r++) {
                int kk = quad*4 + r;
                int jr = __shfl(jid, kk);
                float pe = acc[tt][r] + bias;
                float kv = bf2f(kb[(size_t)jr*128 + cg]);
                float vv = bf2f(vb[(size_t)jr*128 + cg]);
                float a  = qv - kv + pe;
                vpe[tt][r] = vv + pe;
                float o = __shfl_xor(a, 1);
                if ((lane & 1) == 0) {
                    int idx = kk*128 + ((((cg >> 3) ^ (kk & 7))) << 3) + (cg & 7);
                    *(unsigned*)&tb[w][idx] = pack2(a, o);
                }
            }
        }
        // read back a as A-frag
        v8s af2[4];
#pragma unroll
        for (int ks = 0; ks < 4; ks++)
            af2[ks] = *(const v8s*)&tb[w][col*128 + ((((ks*4 + quad) ^ (col & 7))) << 3)];

        // gh = relu(a @ g1 + g1b)
#pragma unroll
        for (int tt = 0; tt < 8; tt++)
#pragma unroll
            for (int rr = 0; rr < 4; rr++) acc[tt][rr] = 0.0f;
#pragma unroll
        for (int ks = 0; ks < 4; ks++) {
#pragma unroll
            for (int tt = 0; tt < 8; tt++) {
                v8s b = *(const v8s*)&g1s[((tt*4 + ks) << 9) + (lane << 3)];
                acc[tt] = __builtin_amdgcn_mfma_f32_16x16x32_bf16(af2[ks], b, acc[tt], 0, 0, 0);
            }
        }
#pragma unroll
        for (int tt = 0; tt < 8; tt++) {
            float bias = g1b[tt*16 + col];
#pragma unroll
            for (int r = 0; r < 4; r++) {
                float h = fmaxf(acc[tt][r] + bias, 0.0f);
                float o = __shfl_xor(h, 1);
                if ((lane & 1) == 0) {
                    int kk = quad*4 + r;
                    int cg = tt*16 + col;
                    int idx = kk*128 + ((((cg >> 3) ^ (kk & 7))) << 3) + (cg & 7);
                    *(unsigned*)&tb[w][idx] = pack2(h, o);
                }
            }
        }
        v8s gf[4];
#pragma unroll
        for (int ks = 0; ks < 4; ks++)
            gf[ks] = *(const v8s*)&tb[w][col*128 + ((((ks*4 + quad) ^ (col & 7))) << 3)];

        // gm = gh @ g2 + g2b
#pragma unroll
        for (int tt = 0; tt < 8; tt++)
#pragma unroll
            for (int rr = 0; rr < 4; rr++) acc[tt][rr] = 0.0f;
#pragma unroll
        for (int ks = 0; ks < 4; ks++) {
#pragma unroll
            for (int tt = 0; tt < 8; tt++) {
                v8s b = *(const v8s*)&g2B[((tt*4 + ks) << 9) + (lane << 3)];
                acc[tt] = __builtin_amdgcn_mfma_f32_16x16x32_bf16(gf[ks], b, acc[tt], 0, 0, 0);
            }
        }

        // softmax over K + attn write + res = sum attn*vpe
        float* resp = (float*)&tb[w][0];
#pragma unroll
        for (int tt = 0; tt < 8; tt++) {
            int cg = tt*16 + col;
            float bias = g2b[cg];
            float l[4];
            float mx = -FLT_MAX;
#pragma unroll
            for (int r = 0; r < 4; r++) {
                l[r] = (acc[tt][r] + bias) * inv_s;
                mx = fmaxf(mx, l[r]);
            }
            mx = fmaxf(mx, __shfl_xor(mx, 16));
            mx = fmaxf(mx, __shfl_xor(mx, 32));
            float s = 0.f;
#pragma unroll
            for (int r = 0; r < 4; r++) { l[r] = __expf(l[r] - mx); s += l[r]; }
            s += __shfl_xor(s, 16);
            s += __shfl_xor(s, 32);
            float rs = 1.0f / s;
            float rp = 0.f;
            size_t base_a = (size_t)(n*16)*128 + cg;
#pragma unroll
            for (int r = 0; r < 4; r++) {
                int kk = quad*4 + r;
                float av = l[r] * rs;
                rp = fmaf(av, vpe[tt][r], rp);
                attn[base_a + (size_t)kk*128] = av;
            }
            rp += __shfl_xor(rp, 16);
            rp += __shfl_xor(rp, 32);
            if (lane < 16) resp[cg] = rp;
        }

        // epilogue: out[n][o] = res @ fc2 + fc2b + x
        int o = lane;
        float acc3 = fc2b[o] + x[(size_t)n*64 + o];
#pragma unroll
        for (int c = 0; c < 128; c += 8) {
            float4 ra = *(const float4*)&resp[c];
            float4 rb = *(const float4*)&resp[c+4];
            uint4 wr = *(const uint4*)&fc2wT[(size_t)o*128 + c];
            acc3 = fmaf(ra.x, bf2f((unsigned short)(wr.x & 0xffff)), acc3);
            acc3 = fmaf(ra.y, bf2f((unsigned short)(wr.x >> 16)),    acc3);
            acc3 = fmaf(ra.z, bf2f((unsigned short)(wr.y & 0xffff)), acc3);
            acc3 = fmaf(ra.w, bf2f((unsigned short)(wr.y >> 16)),    acc3);
            acc3 = fmaf(rb.x, bf2f((unsigned short)(wr.z & 0xffff)), acc3);
            acc3 = fmaf(rb.y, bf2f((unsigned short)(wr.z >> 16)),    acc3);
            acc3 = fmaf(rb.z, bf2f((unsigned short)(wr.w & 0xffff)), acc3);
            acc3 = fmaf(rb.w, bf2f((unsigned short)(wr.w >> 16)),    acc3);
        }
        out[(size_t)n*64 + o] = acc3;
    }
}

// ------------------------------------------------------------------ launch
extern "C" void kernel_launch(void* const* d_in, const int* in_sizes, int n_in,
                              void* d_out, int out_size, void* d_ws, size_t ws_size,
                              hipStream_t stream) {
    (void)in_sizes; (void)n_in; (void)out_size; (void)ws_size;
    const float* x    = (const float*)d_in[0];
    const float* pos  = (const float*)d_in[1];
    const float* fc1w = (const float*)d_in[2];
    const float* fc1b = (const float*)d_in[3];
    const float* fc2w = (const float*)d_in[4];
    const float* fc2b = (const float*)d_in[5];
    const float* d1w  = (const float*)d_in[6];
    const float* d1b  = (const float*)d_in[7];
    const float* d2w  = (const float*)d_in[8];
    const float* d2b  = (const float*)d_in[9];
    const float* g1w  = (const float*)d_in[10];
    const float* g1b  = (const float*)d_in[11];
    const float* g2w  = (const float*)d_in[12];
    const float* g2b  = (const float*)d_in[13];
    const float* wq   = (const float*)d_in[14];
    const float* wk   = (const float*)d_in[15];
    const float* wv   = (const float*)d_in[16];

    float* out      = (float*)d_out;
    float* attn_out = out + (size_t)BN * DIN;

    char* W = (char*)d_ws;
    float4*         pos4  = (float4*)(W + 0);                 // 256 KB
    unsigned short* wB    = (unsigned short*)(W + 262144);    // 96 KB
    unsigned short* fc2wT = (unsigned short*)(W + 360448);    // 16 KB
    int*            knnb  = (int*)(W + 376832);               // 1 MB
    unsigned short* qb    = (unsigned short*)(W + 1441792);   // 4 MB
    unsigned short* kb    = (unsigned short*)(W + 5636096);   // 4 MB
    unsigned short* vb    = (unsigned short*)(W + 9830400);   // 4 MB

    prep_kernel<<<288, 256, 0, stream>>>(pos, d2w, g1w, g2w, fc2w, pos4, wB, fc2wT);
    knn_kernel<<<2048, 256, 0, stream>>>(pos4, knnb);
    feat_kernel<<<1024, 256, 0, stream>>>(x, fc1w, fc1b, wq, wk, wv, qb, kb, vb);
    fused_kernel<<<1024, 256, 0, stream>>>(pos4, knnb, qb, kb, vb, wB, d1w, d1b,
                                           d2b, g1b, g2b, fc2wT, fc2b, x,
                                           out, attn_out);
}

// Round 5
// 756.188 us; speedup vs baseline: 2.1223x; 2.1223x over previous
//
#include <hip/hip_runtime.h>
#include <float.h>

#define NPTS 4096
#define BN   16384
#define DT   128
#define DIN  64

typedef short v8s __attribute__((ext_vector_type(8)));
typedef float v4f __attribute__((ext_vector_type(4)));

__device__ __forceinline__ unsigned short f2bf(float f) {
    union { float f; unsigned u; } v; v.f = f;
    unsigned r = v.u + 0x7fff + ((v.u >> 16) & 1);
    return (unsigned short)(r >> 16);
}
__device__ __forceinline__ float bf2f(unsigned short s) {
    union { unsigned u; float f; } v; v.u = ((unsigned)s) << 16;
    return v.f;
}
__device__ __forceinline__ unsigned pack2(float lo, float hi) {
    return (unsigned)f2bf(lo) | ((unsigned)f2bf(hi) << 16);
}

// ------------------------------------------------------------------ prep
// pos4 = (x,y,z,|p|^2); wB[0..2] = d2w,g1w,g2w in B-fragment swizzled bf16.
__global__ __launch_bounds__(256) void prep_kernel(
    const float* __restrict__ pos, const float* __restrict__ d2w,
    const float* __restrict__ g1w, const float* __restrict__ g2w,
    float4* __restrict__ pos4, unsigned short* __restrict__ wB) {
    int i = blockIdx.x * 256 + threadIdx.x;
    if (i < BN) {
        float p0 = pos[i*3], p1 = pos[i*3+1], p2 = pos[i*3+2];
        pos4[i] = make_float4(p0, p1, p2, fmaf(p2, p2, fmaf(p1, p1, p0*p0)));
    } else if (i < BN + 3*16384) {
        int e = i - BN; int m = e >> 14; e &= 16383;
        int k = e >> 7, n = e & 127;
        const float* W = (m == 0) ? d2w : (m == 1) ? g1w : g2w;
        float val = W[k*128 + n];
        int tile = n >> 4, nl = n & 15, ks = k >> 5, q = (k >> 3) & 3, j = k & 7;
        wB[m*16384 + ((tile*4 + ks)*64 + q*16 + nl)*8 + j] = f2bf(val);
    }
}

// ------------------------------------------------------------------ knn
// Exact top-16 via threshold pruning (tau = 16th smallest of 64 lane-minima
// bounds the true 16th distance; candidates <= tau compacted and sorted).
#define CSW(da,ia,db,ib) { bool sw_ = (da>db)||((da==db)&&(ia>ib)); \
    float td_=sw_?db:da, tD_=sw_?da:db; int ti_=sw_?ib:ia, tI_=sw_?ia:ib; \
    da=td_; db=tD_; ia=ti_; ib=tI_; }

__global__ __launch_bounds__(256, 4) void knn_kernel(const float4* __restrict__ pos4,
                                                     int* __restrict__ knnb) {
    __shared__ float scd[8][256];
    __shared__ int   sci[8][256];
    int t = threadIdx.x, lane = t & 63, w = t >> 6;
    int n0 = blockIdx.x * 8 + w * 2;
    int base = n0 & ~(NPTS - 1);
    float4 pa = pos4[n0], pb = pos4[n0 + 1];

    float mina = FLT_MAX, minb = FLT_MAX;
    for (int m = lane; m < NPTS; m += 64) {
        float4 c = pos4[base + m];
        float da = (pa.w + c.w) - 2.0f * fmaf(pa.z, c.z, fmaf(pa.y, c.y, pa.x*c.x));
        float db = (pb.w + c.w) - 2.0f * fmaf(pb.z, c.z, fmaf(pb.y, c.y, pb.x*c.x));
        mina = fminf(mina, da); minb = fminf(minb, db);
    }
    float taua, taub;
    {
        float cur = mina;
        for (int r = 0; r < 16; r++) {
            float bd = cur;
            for (int off = 32; off; off >>= 1) bd = fminf(bd, __shfl_xor(bd, off, 64));
            taua = bd;
            if (cur == bd) cur = FLT_MAX;
        }
        cur = minb;
        for (int r = 0; r < 16; r++) {
            float bd = cur;
            for (int off = 32; off; off >>= 1) bd = fminf(bd, __shfl_xor(bd, off, 64));
            taub = bd;
            if (cur == bd) cur = FLT_MAX;
        }
    }
    int ca = 0, cb = 0;
    for (int m = lane; m < NPTS; m += 64) {
        float4 c = pos4[base + m];
        float da = (pa.w + c.w) - 2.0f * fmaf(pa.z, c.z, fmaf(pa.y, c.y, pa.x*c.x));
        float db = (pb.w + c.w) - 2.0f * fmaf(pb.z, c.z, fmaf(pb.y, c.y, pb.x*c.x));
        bool ta = da <= taua, tb_ = db <= taub;
        unsigned long long ma = __ballot(ta), mb = __ballot(tb_);
        unsigned long long lower = (1ull << lane) - 1ull;
        if (ta) {
            int p_ = ca + __popcll(ma & lower);
            if (p_ < 256) { scd[w*2][p_] = da; sci[w*2][p_] = base + m; }
        }
        if (tb_) {
            int p_ = cb + __popcll(mb & lower);
            if (p_ < 256) { scd[w*2+1][p_] = db; sci[w*2+1][p_] = base + m; }
        }
        ca += __popcll(ma); cb += __popcll(mb);
    }
    if (ca > 256) ca = 256;
    if (cb > 256) cb = 256;
    for (int i = ca + lane; i < 256; i += 64) { scd[w*2][i]   = FLT_MAX; sci[w*2][i]   = 0x7fffffff; }
    for (int i = cb + lane; i < 256; i += 64) { scd[w*2+1][i] = FLT_MAX; sci[w*2+1][i] = 0x7fffffff; }
    __syncthreads();

    for (int pt = 0; pt < 2; pt++) {
        int s = w*2 + pt;
        float4 dv = *(const float4*)&scd[s][lane*4];
        int4   iv = *(const int4*)&sci[s][lane*4];
        CSW(dv.x, iv.x, dv.y, iv.y);
        CSW(dv.z, iv.z, dv.w, iv.w);
        CSW(dv.x, iv.x, dv.z, iv.z);
        CSW(dv.y, iv.y, dv.w, iv.w);
        CSW(dv.y, iv.y, dv.z, iv.z);
        int p = 0, myres = 0;
        for (int r = 0; r < 16; r++) {
            float hd = p==0 ? dv.x : p==1 ? dv.y : p==2 ? dv.z : p==3 ? dv.w : FLT_MAX;
            int   hi = p==0 ? iv.x : p==1 ? iv.y : p==2 ? iv.z : p==3 ? iv.w : 0x7fffffff;
            float bd = hd; int bi = hi;
            for (int off = 32; off; off >>= 1) {
                float od = __shfl_xor(bd, off, 64);
                int   oi = __shfl_xor(bi, off, 64);
                if (od < bd || (od == bd && oi < bi)) { bd = od; bi = oi; }
            }
            if (hi == bi) p++;
            if (lane == r) myres = bi;
        }
        if (lane < 16) knnb[(n0 + pt)*16 + lane] = myres;
    }
}

// ------------------------------------------------------------------ feat
__global__ __launch_bounds__(256) void feat_kernel(
    const float* __restrict__ x,
    const float* __restrict__ fc1w, const float* __restrict__ fc1b,
    const float* __restrict__ wq, const float* __restrict__ wk,
    const float* __restrict__ wv,
    unsigned short* __restrict__ qb, unsigned short* __restrict__ kb,
    unsigned short* __restrict__ vb) {
    __shared__ float xs[16][64];
    __shared__ float hs[16][128];
    int rb = blockIdx.x * 16;
    int t  = threadIdx.x;

    for (int i = t; i < 16*64; i += 256) xs[i>>6][i&63] = x[rb*64 + i];
    __syncthreads();

    int f4 = (t & 31) * 4;
    int r0 = (t >> 5) * 2, r1 = r0 + 1;
    float a0[4], a1[4];
#pragma unroll
    for (int jf = 0; jf < 4; jf++) { a0[jf] = fc1b[f4+jf]; a1[jf] = fc1b[f4+jf]; }
#pragma unroll 4
    for (int c = 0; c < 64; c += 4) {
        float s0[4], s1[4];
        *(float4*)s0 = *(const float4*)&xs[r0][c];
        *(float4*)s1 = *(const float4*)&xs[r1][c];
#pragma unroll
        for (int jc = 0; jc < 4; jc++) {
            float w[4];
            *(float4*)w = *(const float4*)&fc1w[(c+jc)*128 + f4];
#pragma unroll
            for (int jf = 0; jf < 4; jf++) {
                a0[jf] = fmaf(s0[jc], w[jf], a0[jf]);
                a1[jf] = fmaf(s1[jc], w[jf], a1[jf]);
            }
        }
    }
    *(float4*)&hs[r0][f4] = *(float4*)a0;
    *(float4*)&hs[r1][f4] = *(float4*)a1;
    __syncthreads();

    const float* Ws[3] = { wq, wk, wv };
    unsigned short* Os[3] = { qb, kb, vb };
    for (int mtx = 0; mtx < 3; mtx++) {
        const float* __restrict__ W = Ws[mtx];
#pragma unroll
        for (int jf = 0; jf < 4; jf++) { a0[jf] = 0.f; a1[jf] = 0.f; }
#pragma unroll 4
        for (int c = 0; c < 128; c += 4) {
            float s0[4], s1[4];
            *(float4*)s0 = *(const float4*)&hs[r0][c];
            *(float4*)s1 = *(const float4*)&hs[r1][c];
#pragma unroll
            for (int jc = 0; jc < 4; jc++) {
                float w[4];
                *(float4*)w = *(const float4*)&W[(c+jc)*128 + f4];
#pragma unroll
                for (int jf = 0; jf < 4; jf++) {
                    a0[jf] = fmaf(s0[jc], w[jf], a0[jf]);
                    a1[jf] = fmaf(s1[jc], w[jf], a1[jf]);
                }
            }
        }
        unsigned short* O = Os[mtx];
        uint2 s0v, s1v;
        s0v.x = pack2(a0[0], a0[1]); s0v.y = pack2(a0[2], a0[3]);
        s1v.x = pack2(a1[0], a1[1]); s1v.y = pack2(a1[2], a1[3]);
        *(uint2*)&O[(size_t)(rb+r0)*128 + f4] = s0v;
        *(uint2*)&O[(size_t)(rb+r1)*128 + f4] = s1v;
    }
}

// ------------------------------------------------------------------ fused
// Weight-phased: one 32 KB LDS buffer holds d2 -> g1 -> g2 in turn; per wave
// 4 points; a_in/gh live as A-frag registers, pe as bf16-packed registers.
// Stage1: hd->pe(MFMA d2), a=q-k+pe -> A-frags (LDS transpose).
// Stage2: gh=relu(a@g1) -> A-frags.  Stage3: gm=gh@g2 -> softmax -> attn;
// vpe = v_gather + pe_regs; res = sum attn*vpe -> global (epi kernel does fc2).
__global__ __launch_bounds__(256, 2) void fused_kernel(
    const float4* __restrict__ pos4, const int* __restrict__ knnb,
    const unsigned short* __restrict__ qb, const unsigned short* __restrict__ kb,
    const unsigned short* __restrict__ vb,
    const unsigned short* __restrict__ wB,
    const float* __restrict__ d1w, const float* __restrict__ d1b,
    const float* __restrict__ d2b, const float* __restrict__ g1b,
    const float* __restrict__ g2b,
    float* __restrict__ res, float* __restrict__ attn) {
    __shared__ unsigned short ws_[16384];   // 32 KB staged weight matrix
    __shared__ unsigned short tb[4][2048];  // 4 KB/wave transpose buf
    int t = threadIdx.x;
    int lane = t & 63, w = t >> 6;
    int col = lane & 15, quad = lane >> 4;
    const float inv_s = 0.08838834764831845f;   // 1/sqrt(128)

    // ---- load d2 B-frags
    {
        const uint4* src = (const uint4*)wB;
        uint4* dst = (uint4*)ws_;
        for (int i = t; i < 2048; i += 256) dst[i] = src[i];
    }
    __syncthreads();

    int jid[4];
    v8s frag[4][4];        // a_in A-frags, later gh A-frags
    unsigned peP[4][16];   // pe bf16-packed: [it][tt*2 + (r>>1)]

    // ================= stage 1 =================
    for (int it = 0; it < 4; it++) {
        int n = (blockIdx.x * 4 + w) * 4 + it;
        jid[it] = knnb[n*16 + col];
        float4 pn = pos4[n];
        float4 pj = pos4[jid[it]];
        float r0 = pn.x - pj.x, r1 = pn.y - pj.y, r2 = pn.z - pj.z;

        // hd in A-frag layout
        v8s af[4];
#pragma unroll
        for (int ks = 0; ks < 4; ks++) {
            int fb = ks*32 + quad*8;
            float w0[8], w1[8], w2[8], bb[8];
            *(float4*)&w0[0] = *(const float4*)&d1w[fb];
            *(float4*)&w0[4] = *(const float4*)&d1w[fb+4];
            *(float4*)&w1[0] = *(const float4*)&d1w[128+fb];
            *(float4*)&w1[4] = *(const float4*)&d1w[128+fb+4];
            *(float4*)&w2[0] = *(const float4*)&d1w[256+fb];
            *(float4*)&w2[4] = *(const float4*)&d1w[256+fb+4];
            *(float4*)&bb[0] = *(const float4*)&d1b[fb];
            *(float4*)&bb[4] = *(const float4*)&d1b[fb+4];
#pragma unroll
            for (int j = 0; j < 8; j++) {
                float h = fmaf(r2, w2[j], fmaf(r1, w1[j], fmaf(r0, w0[j], bb[j])));
                af[ks][j] = (short)f2bf(fmaxf(h, 0.0f));
            }
        }

        // pe = hd @ d2
        v4f acc[8];
#pragma unroll
        for (int tt = 0; tt < 8; tt++)
#pragma unroll
            for (int rr = 0; rr < 4; rr++) acc[tt][rr] = 0.0f;
#pragma unroll
        for (int ks = 0; ks < 4; ks++) {
#pragma unroll
            for (int tt = 0; tt < 8; tt++) {
                v8s b = *(const v8s*)&ws_[((tt*4 + ks) << 9) + (lane << 3)];
                acc[tt] = __builtin_amdgcn_mfma_f32_16x16x32_bf16(af[ks], b, acc[tt], 0, 0, 0);
            }
        }

        // a = q - k + pe -> transpose buf; pe -> packed regs
#pragma unroll
        for (int tt = 0; tt < 8; tt++) {
            int cg = tt*16 + col;
            float bias = d2b[cg];
            float qv = bf2f(qb[(size_t)n*128 + cg]);
            float pe0 = 0.f, pe1 = 0.f;
#pragma unroll
            for (int r = 0; r < 4; r++) {
                int kk = quad*4 + r;
                int jr = __shfl(jid[it], kk);
                float pe = acc[tt][r] + bias;
                float kv = bf2f(kb[(size_t)jr*128 + cg]);
                float a  = qv - kv + pe;
                if (r == 0) pe0 = pe;
                if (r == 1) { peP[it][tt*2]   = pack2(pe0, pe); }
                if (r == 2) pe1 = pe;
                if (r == 3) { peP[it][tt*2+1] = pack2(pe1, pe); }
                float o = __shfl_xor(a, 1);
                if ((lane & 1) == 0) {
                    int idx = kk*128 + ((((cg >> 3) ^ (kk & 7))) << 3) + (cg & 7);
                    *(unsigned*)&tb[w][idx] = pack2(a, o);
                }
            }
        }
#pragma unroll
        for (int ks = 0; ks < 4; ks++)
            frag[it][ks] = *(const v8s*)&tb[w][col*128 + ((((ks*4 + quad) ^ (col & 7))) << 3)];
    }

    // ---- swap to g1
    __syncthreads();
    {
        const uint4* src = (const uint4*)(wB + 16384);
        uint4* dst = (uint4*)ws_;
        for (int i = t; i < 2048; i += 256) dst[i] = src[i];
    }
    __syncthreads();

    // ================= stage 2 =================
    for (int it = 0; it < 4; it++) {
        v4f acc[8];
#pragma unroll
        for (int tt = 0; tt < 8; tt++)
#pragma unroll
            for (int rr = 0; rr < 4; rr++) acc[tt][rr] = 0.0f;
#pragma unroll
        for (int ks = 0; ks < 4; ks++) {
#pragma unroll
            for (int tt = 0; tt < 8; tt++) {
                v8s b = *(const v8s*)&ws_[((tt*4 + ks) << 9) + (lane << 3)];
                acc[tt] = __builtin_amdgcn_mfma_f32_16x16x32_bf16(frag[it][ks], b, acc[tt], 0, 0, 0);
            }
        }
#pragma unroll
        for (int tt = 0; tt < 8; tt++) {
            float bias = g1b[tt*16 + col];
#pragma unroll
            for (int r = 0; r < 4; r++) {
                float h = fmaxf(acc[tt][r] + bias, 0.0f);
                float o = __shfl_xor(h, 1);
                if ((lane & 1) == 0) {
                    int kk = quad*4 + r;
                    int cg = tt*16 + col;
                    int idx = kk*128 + ((((cg >> 3) ^ (kk & 7))) << 3) + (cg & 7);
                    *(unsigned*)&tb[w][idx] = pack2(h, o);
                }
            }
        }
#pragma unroll
        for (int ks = 0; ks < 4; ks++)
            frag[it][ks] = *(const v8s*)&tb[w][col*128 + ((((ks*4 + quad) ^ (col & 7))) << 3)];
    }

    // ---- swap to g2
    __syncthreads();
    {
        const uint4* src = (const uint4*)(wB + 32768);
        uint4* dst = (uint4*)ws_;
        for (int i = t; i < 2048; i += 256) dst[i] = src[i];
    }
    __syncthreads();

    // ================= stage 3 =================
    for (int it = 0; it < 4; it++) {
        int n = (blockIdx.x * 4 + w) * 4 + it;
        v4f acc[8];
#pragma unroll
        for (int tt = 0; tt < 8; tt++)
#pragma unroll
            for (int rr = 0; rr < 4; rr++) acc[tt][rr] = 0.0f;
#pragma unroll
        for (int ks = 0; ks < 4; ks++) {
#pragma unroll
            for (int tt = 0; tt < 8; tt++) {
                v8s b = *(const v8s*)&ws_[((tt*4 + ks) << 9) + (lane << 3)];
                acc[tt] = __builtin_amdgcn_mfma_f32_16x16x32_bf16(frag[it][ks], b, acc[tt], 0, 0, 0);
            }
        }

#pragma unroll
        for (int tt = 0; tt < 8; tt++) {
            int cg = tt*16 + col;
            float bias = g2b[cg];
            float l[4];
            float mx = -FLT_MAX;
#pragma unroll
            for (int r = 0; r < 4; r++) {
                l[r] = (acc[tt][r] + bias) * inv_s;
                mx = fmaxf(mx, l[r]);
            }
            mx = fmaxf(mx, __shfl_xor(mx, 16));
            mx = fmaxf(mx, __shfl_xor(mx, 32));
            float s = 0.f;
#pragma unroll
            for (int r = 0; r < 4; r++) { l[r] = __expf(l[r] - mx); s += l[r]; }
            s += __shfl_xor(s, 16);
            s += __shfl_xor(s, 32);
            float rs = 1.0f / s;
            float rp = 0.f;
            size_t base_a = (size_t)(n*16)*128 + cg;
#pragma unroll
            for (int r = 0; r < 4; r++) {
                int kk = quad*4 + r;
                int jr = __shfl(jid[it], kk);
                float vv = bf2f(vb[(size_t)jr*128 + cg]);
                unsigned pp = peP[it][tt*2 + (r >> 1)];
                float pe = bf2f((unsigned short)((r & 1) ? (pp >> 16) : (pp & 0xffff)));
                float av = l[r] * rs;
                rp = fmaf(av, vv + pe, rp);
                attn[base_a + (size_t)kk*128] = av;
            }
            rp += __shfl_xor(rp, 16);
            rp += __shfl_xor(rp, 32);
            if (lane < 16) res[(size_t)n*128 + cg] = rp;
        }
    }
}

// ------------------------------------------------------------------ epi
// out[n][o] = res[n]@fc2 + fc2b[o] + x[n][o]  (fp32, fc2w in LDS)
__global__ __launch_bounds__(256) void epi_kernel(
    const float* __restrict__ res, const float* __restrict__ fc2w,
    const float* __restrict__ fc2b, const float* __restrict__ x,
    float* __restrict__ out) {
    __shared__ float fw[128][64];   // 32 KB
    __shared__ float rs[4][128];
    int t = threadIdx.x;
    for (int i = t; i < 8192; i += 256) fw[i >> 6][i & 63] = fc2w[i];
    __syncthreads();

    int o = t & 63, g = t >> 6;
    for (int iter = 0; iter < 16; iter++) {
        int n = blockIdx.x * 64 + iter * 4 + g;
        rs[g][o]      = res[(size_t)n*128 + o];
        rs[g][64 + o] = res[(size_t)n*128 + 64 + o];
        __syncthreads();
        float acc = fc2b[o] + x[(size_t)n*64 + o];
#pragma unroll 16
        for (int c = 0; c < 128; c++) acc = fmaf(rs[g][c], fw[c][o], acc);
        out[(size_t)n*64 + o] = acc;
        __syncthreads();
    }
}

// ------------------------------------------------------------------ launch
extern "C" void kernel_launch(void* const* d_in, const int* in_sizes, int n_in,
                              void* d_out, int out_size, void* d_ws, size_t ws_size,
                              hipStream_t stream) {
    (void)in_sizes; (void)n_in; (void)out_size; (void)ws_size;
    const float* x    = (const float*)d_in[0];
    const float* pos  = (const float*)d_in[1];
    const float* fc1w = (const float*)d_in[2];
    const float* fc1b = (const float*)d_in[3];
    const float* fc2w = (const float*)d_in[4];
    const float* fc2b = (const float*)d_in[5];
    const float* d1w  = (const float*)d_in[6];
    const float* d1b  = (const float*)d_in[7];
    const float* d2w  = (const float*)d_in[8];
    const float* d2b  = (const float*)d_in[9];
    const float* g1w  = (const float*)d_in[10];
    const float* g1b  = (const float*)d_in[11];
    const float* g2w  = (const float*)d_in[12];
    const float* g2b  = (const float*)d_in[13];
    const float* wq   = (const float*)d_in[14];
    const float* wk   = (const float*)d_in[15];
    const float* wv   = (const float*)d_in[16];

    float* out      = (float*)d_out;
    float* attn_out = out + (size_t)BN * DIN;

    char* W = (char*)d_ws;
    float4*         pos4  = (float4*)(W + 0);                 // 256 KB
    unsigned short* wB    = (unsigned short*)(W + 262144);    // 96 KB
    int*            knnb  = (int*)(W + 376832);               // 1 MB
    unsigned short* qb    = (unsigned short*)(W + 1441792);   // 4 MB
    unsigned short* kb    = (unsigned short*)(W + 5636096);   // 4 MB
    unsigned short* vb    = (unsigned short*)(W + 9830400);   // 4 MB
    float*          res   = (float*)(W + 14024704);           // 8 MB

    prep_kernel<<<256, 256, 0, stream>>>(pos, d2w, g1w, g2w, pos4, wB);
    knn_kernel<<<2048, 256, 0, stream>>>(pos4, knnb);
    feat_kernel<<<1024, 256, 0, stream>>>(x, fc1w, fc1b, wq, wk, wv, qb, kb, vb);
    fused_kernel<<<1024, 256, 0, stream>>>(pos4, knnb, qb, kb, vb, wB, d1w, d1b,
                                           d2b, g1b, g2b, res, attn_out);
    epi_kernel<<<256, 256, 0, stream>>>(res, fc2w, fc2b, x, out);
}